// Round 3
// baseline (250.341 us; speedup 1.0000x reference)
//
#include <hip/hip_runtime.h>
#include <hip/hip_bf16.h>
#include <stdint.h>

// Problem: B=32, N=2048, D=512, K=64, G=16, M=B*N=65536, C=K+G=80
// Inputs fp32; OUTPUT fp32.
typedef __attribute__((ext_vector_type(8))) short short8;
typedef __attribute__((ext_vector_type(4))) float f32x4;

__device__ __forceinline__ float b2f(uint16_t u) {
  union { uint32_t i; float f; } v; v.i = ((uint32_t)u) << 16; return v.f;
}
__device__ __forceinline__ uint16_t f2b(float f) {   // RNE fp32->bf16
  uint32_t u = __float_as_uint(f);
  return (uint16_t)((u + 0x7FFFu + ((u >> 16) & 1u)) >> 16);
}
// pack two fp32 bit-patterns -> bf16x2 (lo in low half) via v_perm
__device__ __forceinline__ uint32_t pk2(uint32_t lo, uint32_t hi) {
  return __builtin_amdgcn_perm(hi + 0x8000u, lo + 0x8000u, 0x07060302u);
}

// ---------------------------------------------------------------------------
// K0: clusters fp32 [512][80] -> bf16 MFMA B-fragments, [chunk][q][lr] order:
// cB[(((kk*5+n)*4+q)*16+lr)*8+i] = clusters[kk*32+q*8+i][n*16+lr]
// ---------------------------------------------------------------------------
__global__ void k0_prep(const float* __restrict__ clusters,
                        uint16_t* __restrict__ cB) {
  int gid = blockIdx.x * 256 + threadIdx.x;
  if (gid < 40960) {
    int i = gid & 7, chunk = gid >> 3;
    int lr = chunk & 15, q = (chunk >> 4) & 3, c5 = chunk >> 6;
    int n = c5 % 5, kk = c5 / 5;
    cB[gid] = f2b(clusters[(kk * 32 + q * 8 + i) * 80 + n * 16 + lr]);
  }
}

// ---------------------------------------------------------------------------
// K1: raw[65536][80] = bf16(x) @ bf16(clusters)  (MFMA 16x16x32)
//     + per-block column sum/sumsq partials (part TRANSPOSED: part[c][blk]).
// v3: m=1 (64 rows/block, grid 1024), __launch_bounds__(256,4) caps VGPR
// at 128 -> 4 blocks/CU = 16 waves/CU (2x TLP vs v2). Explicit 2-deep x
// prefetch + 1-deep cB prefetch: every load issued >=1 full iter before use.
// ---------------------------------------------------------------------------
__global__ __launch_bounds__(256, 4) void k1_gemm1(
    const float* __restrict__ x, const uint16_t* __restrict__ cB,
    float* __restrict__ raw, float* __restrict__ part) {
  __shared__ float sf[1280];
  const int t = threadIdx.x;
  const int w = t >> 6, lane = t & 63, q = lane >> 4, lr = lane & 15;
  const int rbase = blockIdx.x * 64 + w * 16;

  f32x4 acc[5];
#pragma unroll
  for (int n = 0; n < 5; ++n) acc[n] = 0.f;

  const float* xa = x + (size_t)(rbase + lr) * 512 + q * 8;
  const short8* cbq = (const short8*)cB + q * 16 + lr;  // + (kk*5+n)*64

  uint4 u0[2], u1[2];
  u0[0] = *(const uint4*)(xa);          u1[0] = *(const uint4*)(xa + 4);
  u0[1] = *(const uint4*)(xa + 32);     u1[1] = *(const uint4*)(xa + 36);
  short8 bfc[5], bfp[5];
#pragma unroll
  for (int n = 0; n < 5; ++n) bfc[n] = cbq[n * 64];

#pragma unroll
  for (int kk = 0; kk < 16; ++kk) {
    const int si = kk & 1;
    union { short8 s; uint32_t u[4]; } av;
    av.u[0] = pk2(u0[si].x, u0[si].y); av.u[1] = pk2(u0[si].z, u0[si].w);
    av.u[2] = pk2(u1[si].x, u1[si].y); av.u[3] = pk2(u1[si].z, u1[si].w);
    if (kk < 15) {
#pragma unroll
      for (int n = 0; n < 5; ++n) bfp[n] = cbq[((kk + 1) * 5 + n) * 64];
    }
    if (kk < 14) {
      u0[si] = *(const uint4*)(xa + (kk + 2) * 32);
      u1[si] = *(const uint4*)(xa + (kk + 2) * 32 + 4);
    }
#pragma unroll
    for (int n = 0; n < 5; ++n)
      acc[n] = __builtin_amdgcn_mfma_f32_16x16x32_bf16(av.s, bfc[n], acc[n], 0, 0, 0);
#pragma unroll
    for (int n = 0; n < 5; ++n) bfc[n] = bfp[n];
  }

  float sums[5], sqs[5];
#pragma unroll
  for (int n = 0; n < 5; ++n) {
    float s = 0.f, qq = 0.f;
#pragma unroll
    for (int r = 0; r < 4; ++r) {
      float v = acc[n][r];
      s += v; qq += v * v;
      raw[(size_t)(rbase + q * 4 + r) * 80 + n * 16 + lr] = v;
    }
    s += __shfl_xor(s, 16);  s += __shfl_xor(s, 32);
    qq += __shfl_xor(qq, 16); qq += __shfl_xor(qq, 32);
    sums[n] = s; sqs[n] = qq;
  }

  if (lane < 16) {
#pragma unroll
    for (int n = 0; n < 5; ++n) {
      sf[w * 160 + n * 16 + lr] = sums[n];
      sf[640 + w * 160 + n * 16 + lr] = sqs[n];
    }
  }
  __syncthreads();
  if (t < 160) {
    float a0 = sf[t] + sf[160 + t] + sf[320 + t] + sf[480 + t];
    float b0 = sf[640 + t] + sf[800 + t] + sf[960 + t] + sf[1120 + t];
    part[(size_t)t * 1024 + blockIdx.x] = a0;            // transposed layout
    part[(size_t)(160 + t) * 1024 + blockIdx.x] = b0;
  }
}

// ---------------------------------------------------------------------------
// K2: BN stats -> scale[80] | shift[80]. grid 80 x 64. Coalesced reads.
// ---------------------------------------------------------------------------
__global__ __launch_bounds__(64) void k2_stats(
    const float* __restrict__ part, const float* __restrict__ gamma,
    const float* __restrict__ beta, float* __restrict__ scsh) {
  int c = blockIdx.x, t = threadIdx.x;
  const float* p1 = part + (size_t)c * 1024;
  const float* p2 = part + (size_t)(160 + c) * 1024;
  float s1 = 0.f, s2 = 0.f;
#pragma unroll
  for (int p = 0; p < 1024; p += 64) { s1 += p1[p + t]; s2 += p2[p + t]; }
#pragma unroll
  for (int o = 1; o < 64; o <<= 1) { s1 += __shfl_xor(s1, o); s2 += __shfl_xor(s2, o); }
  if (t == 0) {
    float mean = s1 * (1.f / 65536.f);
    float var = s2 * (1.f / 65536.f) - mean * mean;
    float sc = rsqrtf(var + 1e-5f) * gamma[c];
    scsh[c] = sc;
    scsh[80 + c] = beta[c] - mean * sc;
  }
}

// ---------------------------------------------------------------------------
// k34: fused BN + softmax + GEMM2. ONE barrier per chunk: stage(c+1 -> buf^1)
// and GEMM(c -> buf) touch disjoint buffers, so they share a phase and the
// stage VALU work (pk2/expf) overlaps MFMA issue across waves.
// grid 512 = b(32) x s(8 n-slices of 256) x dh(2 d-halves of 256); 256 thr.
// vpart[s][b][d][k] partials; apart[b][s][k] = per-slice sum of p (bf16-
// consistent with the GEMM operand).
// ---------------------------------------------------------------------------
__global__ __launch_bounds__(256, 2) void k34_fused(
    const float* __restrict__ x, const float* __restrict__ raw_,
    const float* __restrict__ scsh, float* __restrict__ vpart,
    float* __restrict__ apart) {
  __shared__ __align__(16) uint16_t sx[2][256 * 40];  // 40,960 B  [d][n] bf16
  __shared__ __align__(16) uint16_t sp[2][64 * 40];   // 10,240 B  [k][n] bf16
  __shared__ float sc[80], sh[80];
  __shared__ float ared[4 * 64];

  const int t = threadIdx.x;
  const int b = blockIdx.x >> 4;
  const int s = (blockIdx.x >> 1) & 7;
  const int dh = blockIdx.x & 1;
  const int w = t >> 6, lane = t & 63, q = lane >> 4, lr = lane & 15;

  const int dd = t;                                   // staged d column 0..255
  const int sg = ((dd >> 2) + (dd >> 4)) & 3;         // write octet swizzle
  const int r_ = t >> 3, cg = t & 7;                  // softmax: row, 10-col grp
  const int kk_ = t & 63, ng = t >> 6;                // a_sum: k, n-octet group

  if (t < 80) sc[t] = scsh[t];
  else if (t < 160) sh[t - 80] = scsh[t];

  const float* xb = x + ((size_t)b * 2048 + (size_t)s * 256) * 512 + dh * 256;
  const float* rawb = raw_ + ((size_t)b * 2048 + (size_t)s * 256) * 80;

  f32x4 acc[4][4];
#pragma unroll
  for (int m = 0; m < 4; ++m)
#pragma unroll
    for (int j = 0; j < 4; ++j) acc[m][j] = 0.f;

  float xf[32], yf[10];
  float asum = 0.f;

#define XLOAD(c)                                                          \
  {                                                                       \
    const float* xc = xb + (size_t)(c) * 32 * 512 + dd;                   \
    _Pragma("unroll")                                                     \
    for (int j = 0; j < 32; ++j) xf[j] = xc[(size_t)j * 512];             \
  }
#define RLOAD(c)                                                          \
  {                                                                       \
    const float* rc = rawb + (size_t)((c) * 32 + r_) * 80 + cg * 10;      \
    _Pragma("unroll")                                                     \
    for (int j = 0; j < 5; ++j) {                                         \
      float2 v2 = *(const float2*)(rc + j * 2);                           \
      yf[2 * j] = v2.x; yf[2 * j + 1] = v2.y;                             \
    }                                                                     \
  }
#define XSTORE(buf)                                                       \
  {                                                                       \
    _Pragma("unroll")                                                     \
    for (int g = 0; g < 4; ++g) {                                         \
      union { uint4 u; uint32_t w4[4]; } pv;                              \
      _Pragma("unroll")                                                   \
      for (int h = 0; h < 4; ++h)                                         \
        pv.w4[h] = pk2(__float_as_uint(xf[g * 8 + h * 2]),                \
                       __float_as_uint(xf[g * 8 + h * 2 + 1]));           \
      *(uint4*)&sx[buf][dd * 40 + ((g ^ sg) << 3)] = pv.u;                \
    }                                                                     \
  }
#define SOFTMAX(buf)                                                      \
  {                                                                       \
    float yy[10]; float mx = -3.0e38f;                                    \
    _Pragma("unroll")                                                     \
    for (int j = 0; j < 10; ++j) {                                        \
      int cc = cg * 10 + j;                                               \
      yy[j] = yf[j] * sc[cc] + sh[cc];                                    \
      mx = fmaxf(mx, yy[j]);                                              \
    }                                                                     \
    mx = fmaxf(mx, __shfl_xor(mx, 1));                                    \
    mx = fmaxf(mx, __shfl_xor(mx, 2));                                    \
    mx = fmaxf(mx, __shfl_xor(mx, 4));                                    \
    float sum = 0.f;                                                      \
    _Pragma("unroll")                                                     \
    for (int j = 0; j < 10; ++j) { yy[j] = __expf(yy[j] - mx); sum += yy[j]; } \
    sum += __shfl_xor(sum, 1);                                            \
    sum += __shfl_xor(sum, 2);                                            \
    sum += __shfl_xor(sum, 4);                                            \
    float inv = 1.0f / sum;                                               \
    _Pragma("unroll")                                                     \
    for (int j = 0; j < 10; ++j) {                                        \
      int cc = cg * 10 + j;                                               \
      if (cc < 64) sp[buf][cc * 40 + r_] = f2b(yy[j] * inv);              \
    }                                                                     \
  }
#define GEMM(buf)                                                         \
  {                                                                       \
    const uint16_t* sxc = sx[buf];                                        \
    const uint16_t* spc = sp[buf];                                        \
    short8 bfr[4];                                                        \
    _Pragma("unroll")                                                     \
    for (int j = 0; j < 4; ++j)                                           \
      bfr[j] = *(const short8*)&spc[(j * 16 + lr) * 40 + (q << 3)];       \
    _Pragma("unroll")                                                     \
    for (int m = 0; m < 4; ++m) {                                         \
      int row = w * 64 + m * 16 + lr;                                     \
      int swr = ((row >> 2) + (row >> 4)) & 3;                            \
      short8 af = *(const short8*)&sxc[row * 40 + ((q ^ swr) << 3)];      \
      _Pragma("unroll")                                                   \
      for (int j = 0; j < 4; ++j)                                         \
        acc[m][j] = __builtin_amdgcn_mfma_f32_16x16x32_bf16(af, bfr[j], acc[m][j], 0, 0, 0); \
    }                                                                     \
    union { uint4 u; uint16_t us[8]; } pv;                                \
    pv.u = *(const uint4*)&spc[kk_ * 40 + (ng << 3)];                     \
    _Pragma("unroll")                                                     \
    for (int i = 0; i < 8; ++i) asum += b2f(pv.us[i]);                    \
  }

  XLOAD(0) RLOAD(0)
  __syncthreads();                 // sc/sh visible
  XSTORE(0) SOFTMAX(0)            // stage chunk0 -> buf0
  XLOAD(1) RLOAD(1)               // prefetch chunk1
  __syncthreads();                 // buf0 published

  for (int c = 0; c < 8; ++c) {
    const int cur = c & 1;
    if (c < 7) {
      XSTORE(cur ^ 1) SOFTMAX(cur ^ 1)   // stage chunk c+1 (disjoint buffer)
      if (c < 6) { XLOAD(c + 2) RLOAD(c + 2) }
    }
    GEMM(cur)
    __syncthreads();               // buf cur free for re-stage; buf cur^1 ready
  }
#undef XLOAD
#undef RLOAD
#undef XSTORE
#undef SOFTMAX
#undef GEMM

  ared[ng * 64 + kk_] = asum;
  __syncthreads();
  if (dh == 0 && t < 64) {
    float a = ared[t] + ared[64 + t] + ared[128 + t] + ared[192 + t];
    apart[((size_t)b * 8 + s) * 64 + t] = a;
  }

  float* vp = vpart + ((size_t)s * 32 + b) * 32768;
#pragma unroll
  for (int m = 0; m < 4; ++m)
#pragma unroll
    for (int j = 0; j < 4; ++j)
#pragma unroll
      for (int r2 = 0; r2 < 4; ++r2)
        vp[(size_t)(dh * 256 + w * 64 + m * 16 + q * 4 + r2) * 64 + j * 16 + lr] =
            acc[m][j][r2];
}

// ---------------------------------------------------------------------------
// K5a: v = sum_s vpart[s] - a_sum*c2 ; write vfull + partial column sumsq.
// float4 over k (16B/lane loads). grid 512 (32 b x 16 dg) x 256.
// ---------------------------------------------------------------------------
__global__ __launch_bounds__(256) void k5a_red(
    const float* __restrict__ vpart, const float* __restrict__ apart,
    const float* __restrict__ c2, float* __restrict__ vfull,
    float* __restrict__ csq) {
  __shared__ float las[64];
  __shared__ float sred[16 * 64];
  const int t = threadIdx.x, b = blockIdx.x >> 4, dg = blockIdx.x & 15;
  if (t < 64) {
    float a = 0.f;
#pragma unroll
    for (int s = 0; s < 8; ++s) a += apart[((size_t)b * 8 + s) * 64 + t];
    las[t] = a;
  }
  __syncthreads();
  const int di = t >> 4, kq = t & 15;
  const float4 lasv = *(const float4*)&las[kq * 4];
  float4 ssq = {0.f, 0.f, 0.f, 0.f};
#pragma unroll
  for (int jj = 0; jj < 2; ++jj) {
    int d = dg * 32 + jj * 16 + di;
    size_t i = (size_t)d * 64 + kq * 4;
    float4 cc = *(const float4*)(c2 + i);
    float4 v;
    v.x = -lasv.x * cc.x; v.y = -lasv.y * cc.y;
    v.z = -lasv.z * cc.z; v.w = -lasv.w * cc.w;
#pragma unroll
    for (int s = 0; s < 8; ++s) {
      float4 p = *(const float4*)(vpart + ((size_t)s * 32 + b) * 32768 + i);
      v.x += p.x; v.y += p.y; v.z += p.z; v.w += p.w;
    }
    *(float4*)(vfull + (size_t)b * 32768 + i) = v;
    ssq.x += v.x * v.x; ssq.y += v.y * v.y;
    ssq.z += v.z * v.z; ssq.w += v.w * v.w;
  }
  *(float4*)&sred[di * 64 + kq * 4] = ssq;
  __syncthreads();
  if (t < 64) {
    float s0 = 0.f;
#pragma unroll
    for (int di2 = 0; di2 < 16; ++di2) s0 += sred[di2 * 64 + t];
    csq[(size_t)blockIdx.x * 64 + t] = s0;
  }
}

// ---------------------------------------------------------------------------
// K5c: linv/gscl recomputed per block from csq (4KB, L2-hot) -> k5b deleted.
// out = vfull * linv[k] * gscl[b]. grid 512 (32b x 16seg) x 256.
// ---------------------------------------------------------------------------
__global__ __launch_bounds__(256) void k5c_norm(
    const float* __restrict__ csq, const float* __restrict__ vfull,
    float* __restrict__ out) {
  __shared__ float lv[64];
  __shared__ float gsv;
  const int t = threadIdx.x, b = blockIdx.x >> 4, seg = blockIdx.x & 15;
  if (t < 64) {                       // wave 0 computes linv + gscl for b
    float ssq = 0.f;
#pragma unroll
    for (int dg = 0; dg < 16; ++dg) ssq += csq[(size_t)(b * 16 + dg) * 64 + t];
    float iv = 1.0f / fmaxf(sqrtf(ssq), 1e-12f);
    lv[t] = iv;
    float contrib = ssq * iv * iv;
#pragma unroll
    for (int o = 1; o < 64; o <<= 1) contrib += __shfl_xor(contrib, o);
    if (t == 0) gsv = 1.0f / fmaxf(sqrtf(contrib), 1e-12f);
  }
  __syncthreads();
  const float gg = gsv;
#pragma unroll
  for (int u = 0; u < 2; ++u) {
    int i = seg * 2048 + u * 1024 + t * 4;
    int k0 = i & 63;
    float4 a = *(const float4*)(vfull + (size_t)b * 32768 + i);
    float4 o;
    o.x = a.x * lv[k0 + 0] * gg;
    o.y = a.y * lv[k0 + 1] * gg;
    o.z = a.z * lv[k0 + 2] * gg;
    o.w = a.w * lv[k0 + 3] * gg;
    *(float4*)&out[(size_t)b * 32768 + i] = o;
  }
}

// ---------------------------------------------------------------------------
// Workspace (bytes), total 60,310,144:
//   cB    @ 0        : 81,920
//   part  @ 81920    : 320*1024*4   =  1,310,720
//   scsh  @ 1392640  : 640
//   raw   @ 1393280  : 65536*80*4   = 20,971,520
//   vpart @ 22364800 : 8*32*32768*4 = 33,554,432
//   vfull @ 55919232 : 32*32768*4   =  4,194,304
//   apart @ 60113536 : 32*8*64*4    =     65,536
//   csq   @ 60179072 : 512*64*4     =    131,072
// ---------------------------------------------------------------------------
extern "C" void kernel_launch(void* const* d_in, const int* in_sizes, int n_in,
                              void* d_out, int out_size, void* d_ws, size_t ws_size,
                              hipStream_t stream) {
  const float* x         = (const float*)d_in[0];
  const float* clusters  = (const float*)d_in[1];
  const float* clusters2 = (const float*)d_in[2];
  const float* gamma     = (const float*)d_in[3];
  const float* beta      = (const float*)d_in[4];
  float* out = (float*)d_out;
  char* ws = (char*)d_ws;

  uint16_t* cB = (uint16_t*)(ws + 0);
  float* part  = (float*)(ws + 81920);
  float* scsh  = (float*)(ws + 1392640);
  float* raw   = (float*)(ws + 1393280);
  float* vpart = (float*)(ws + 22364800);
  float* vfull = (float*)(ws + 55919232);
  float* apart = (float*)(ws + 60113536);
  float* csq   = (float*)(ws + 60179072);

  hipLaunchKernelGGL(k0_prep,   dim3(160),  dim3(256), 0, stream, clusters, cB);
  hipLaunchKernelGGL(k1_gemm1,  dim3(1024), dim3(256), 0, stream, x, cB, raw, part);
  hipLaunchKernelGGL(k2_stats,  dim3(80),   dim3(64),  0, stream, part, gamma, beta, scsh);
  hipLaunchKernelGGL(k34_fused, dim3(512),  dim3(256), 0, stream, x, raw, scsh, vpart, apart);
  hipLaunchKernelGGL(k5a_red,   dim3(512),  dim3(256), 0, stream, vpart, apart, clusters2, vfull, csq);
  hipLaunchKernelGGL(k5c_norm,  dim3(512),  dim3(256), 0, stream, csq, vfull, out);
}

// Round 4
// 245.481 us; speedup vs baseline: 1.0198x; 1.0198x over previous
//
#include <hip/hip_runtime.h>
#include <hip/hip_bf16.h>
#include <stdint.h>

// Problem: B=32, N=2048, D=512, K=64, G=16, M=B*N=65536, C=K+G=80
// Inputs fp32; OUTPUT fp32.
typedef __attribute__((ext_vector_type(8))) short short8;
typedef __attribute__((ext_vector_type(4))) float f32x4;

__device__ __forceinline__ float b2f(uint16_t u) {
  union { uint32_t i; float f; } v; v.i = ((uint32_t)u) << 16; return v.f;
}
__device__ __forceinline__ uint16_t f2b(float f) {   // RNE fp32->bf16
  uint32_t u = __float_as_uint(f);
  return (uint16_t)((u + 0x7FFFu + ((u >> 16) & 1u)) >> 16);
}
// pack two fp32 bit-patterns -> bf16x2 (lo in low half) via v_perm
__device__ __forceinline__ uint32_t pk2(uint32_t lo, uint32_t hi) {
  return __builtin_amdgcn_perm(hi + 0x8000u, lo + 0x8000u, 0x07060302u);
}

// ---------------------------------------------------------------------------
// K0: clusters fp32 [512][80] -> bf16 MFMA B-fragments, [chunk][q][lr] order:
// cB[(((kk*5+n)*4+q)*16+lr)*8+i] = clusters[kk*32+q*8+i][n*16+lr]
// ---------------------------------------------------------------------------
__global__ void k0_prep(const float* __restrict__ clusters,
                        uint16_t* __restrict__ cB) {
  int gid = blockIdx.x * 256 + threadIdx.x;
  if (gid < 40960) {
    int i = gid & 7, chunk = gid >> 3;
    int lr = chunk & 15, q = (chunk >> 4) & 3, c5 = chunk >> 6;
    int n = c5 % 5, kk = c5 / 5;
    cB[gid] = f2b(clusters[(kk * 32 + q * 8 + i) * 80 + n * 16 + lr]);
  }
}

// ---------------------------------------------------------------------------
// K1: raw[65536][80] = bf16(x) @ bf16(clusters)  (MFMA 16x16x32)
//     + per-block column sum/sumsq partials (part TRANSPOSED: part[c][blk]).
// m=1 (64 rows/block, grid 1024), __launch_bounds__(256,4); 2-deep x
// prefetch + 1-deep cB prefetch. (R3 version, kept: occupancy-insensitive.)
// ---------------------------------------------------------------------------
__global__ __launch_bounds__(256, 4) void k1_gemm1(
    const float* __restrict__ x, const uint16_t* __restrict__ cB,
    float* __restrict__ raw, float* __restrict__ part) {
  __shared__ float sf[1280];
  const int t = threadIdx.x;
  const int w = t >> 6, lane = t & 63, q = lane >> 4, lr = lane & 15;
  const int rbase = blockIdx.x * 64 + w * 16;

  f32x4 acc[5];
#pragma unroll
  for (int n = 0; n < 5; ++n) acc[n] = 0.f;

  const float* xa = x + (size_t)(rbase + lr) * 512 + q * 8;
  const short8* cbq = (const short8*)cB + q * 16 + lr;  // + (kk*5+n)*64

  uint4 u0[2], u1[2];
  u0[0] = *(const uint4*)(xa);          u1[0] = *(const uint4*)(xa + 4);
  u0[1] = *(const uint4*)(xa + 32);     u1[1] = *(const uint4*)(xa + 36);
  short8 bfc[5], bfp[5];
#pragma unroll
  for (int n = 0; n < 5; ++n) bfc[n] = cbq[n * 64];

#pragma unroll
  for (int kk = 0; kk < 16; ++kk) {
    const int si = kk & 1;
    union { short8 s; uint32_t u[4]; } av;
    av.u[0] = pk2(u0[si].x, u0[si].y); av.u[1] = pk2(u0[si].z, u0[si].w);
    av.u[2] = pk2(u1[si].x, u1[si].y); av.u[3] = pk2(u1[si].z, u1[si].w);
    if (kk < 15) {
#pragma unroll
      for (int n = 0; n < 5; ++n) bfp[n] = cbq[((kk + 1) * 5 + n) * 64];
    }
    if (kk < 14) {
      u0[si] = *(const uint4*)(xa + (kk + 2) * 32);
      u1[si] = *(const uint4*)(xa + (kk + 2) * 32 + 4);
    }
#pragma unroll
    for (int n = 0; n < 5; ++n)
      acc[n] = __builtin_amdgcn_mfma_f32_16x16x32_bf16(av.s, bfc[n], acc[n], 0, 0, 0);
#pragma unroll
    for (int n = 0; n < 5; ++n) bfc[n] = bfp[n];
  }

  float sums[5], sqs[5];
#pragma unroll
  for (int n = 0; n < 5; ++n) {
    float s = 0.f, qq = 0.f;
#pragma unroll
    for (int r = 0; r < 4; ++r) {
      float v = acc[n][r];
      s += v; qq += v * v;
      raw[(size_t)(rbase + q * 4 + r) * 80 + n * 16 + lr] = v;
    }
    s += __shfl_xor(s, 16);  s += __shfl_xor(s, 32);
    qq += __shfl_xor(qq, 16); qq += __shfl_xor(qq, 32);
    sums[n] = s; sqs[n] = qq;
  }

  if (lane < 16) {
#pragma unroll
    for (int n = 0; n < 5; ++n) {
      sf[w * 160 + n * 16 + lr] = sums[n];
      sf[640 + w * 160 + n * 16 + lr] = sqs[n];
    }
  }
  __syncthreads();
  if (t < 160) {
    float a0 = sf[t] + sf[160 + t] + sf[320 + t] + sf[480 + t];
    float b0 = sf[640 + t] + sf[800 + t] + sf[960 + t] + sf[1120 + t];
    part[(size_t)t * 1024 + blockIdx.x] = a0;            // transposed layout
    part[(size_t)(160 + t) * 1024 + blockIdx.x] = b0;
  }
}

// ---------------------------------------------------------------------------
// K2: BN stats -> scale[80] | shift[80]. grid 80 x 64. Coalesced reads.
// ---------------------------------------------------------------------------
__global__ __launch_bounds__(64) void k2_stats(
    const float* __restrict__ part, const float* __restrict__ gamma,
    const float* __restrict__ beta, float* __restrict__ scsh) {
  int c = blockIdx.x, t = threadIdx.x;
  const float* p1 = part + (size_t)c * 1024;
  const float* p2 = part + (size_t)(160 + c) * 1024;
  float s1 = 0.f, s2 = 0.f;
#pragma unroll
  for (int p = 0; p < 1024; p += 64) { s1 += p1[p + t]; s2 += p2[p + t]; }
#pragma unroll
  for (int o = 1; o < 64; o <<= 1) { s1 += __shfl_xor(s1, o); s2 += __shfl_xor(s2, o); }
  if (t == 0) {
    float mean = s1 * (1.f / 65536.f);
    float var = s2 * (1.f / 65536.f) - mean * mean;
    float sc = rsqrtf(var + 1e-5f) * gamma[c];
    scsh[c] = sc;
    scsh[80 + c] = beta[c] - mean * sc;
  }
}

// ---------------------------------------------------------------------------
// k34: fused BN + softmax + GEMM2. One barrier per chunk (stage c+1 || GEMM c
// on disjoint buffers). R4 changes:
//  - XLOAD is dwordx4 (8x float4 along d per thread; 4x fewer VMEM instrs,
//    bit-identical values/pairing).
//  - decode: dh = blockIdx>>8 -> the two blocks sharing a raw slice are 256
//    apart => same XCD (256 % 8 == 0), raw re-read hits that XCD's L2.
//  - s_setprio(1) around the MFMA cluster (T5; 2 blocks/CU role diversity).
// grid 512 = dh(2) x s(8 n-slices of 256) x b(32); 256 thr.
// vpart[s][b][d][k] partials; apart[b][s][k] = per-slice sum of p.
// ---------------------------------------------------------------------------
__global__ __launch_bounds__(256, 2) void k34_fused(
    const float* __restrict__ x, const float* __restrict__ raw_,
    const float* __restrict__ scsh, float* __restrict__ vpart,
    float* __restrict__ apart) {
  __shared__ __align__(16) uint16_t sx[2][256 * 40];  // 40,960 B  [d][n] bf16
  __shared__ __align__(16) uint16_t sp[2][64 * 40];   // 10,240 B  [k][n] bf16
  __shared__ float sc[80], sh[80];
  __shared__ float ared[4 * 64];

  const int t = threadIdx.x;
  const int b = blockIdx.x & 31;
  const int s = (blockIdx.x >> 5) & 7;
  const int dh = blockIdx.x >> 8;
  const int w = t >> 6, lane = t & 63, q = lane >> 4, lr = lane & 15;

  const int dq = t & 63, g = t >> 6;                  // x staging: d-quad, n-octet
  const int sgq = (dq + (dq >> 2)) & 3;               // swizzle slot (same for e=0..3)
  const int r_ = t >> 3, cg = t & 7;                  // softmax: row, 10-col grp
  const int kk_ = t & 63, ng = t >> 6;                // a_sum: k, n-octet group

  if (t < 80) sc[t] = scsh[t];
  else if (t < 160) sh[t - 80] = scsh[t];

  const float* xb = x + ((size_t)b * 2048 + (size_t)s * 256) * 512 + dh * 256;
  const float* rawb = raw_ + ((size_t)b * 2048 + (size_t)s * 256) * 80;

  f32x4 acc[4][4];
#pragma unroll
  for (int m = 0; m < 4; ++m)
#pragma unroll
    for (int j = 0; j < 4; ++j) acc[m][j] = 0.f;

  f32x4 xf4[8];
  float yf[10];
  float asum = 0.f;

#define XLOAD(c)                                                          \
  {                                                                       \
    const float* xc = xb + (size_t)((c) * 32 + g * 8) * 512 + dq * 4;     \
    _Pragma("unroll")                                                     \
    for (int jj = 0; jj < 8; ++jj)                                        \
      xf4[jj] = *(const f32x4*)(xc + (size_t)jj * 512);                   \
  }
#define RLOAD(c)                                                          \
  {                                                                       \
    const float* rc = rawb + (size_t)((c) * 32 + r_) * 80 + cg * 10;      \
    _Pragma("unroll")                                                     \
    for (int j = 0; j < 5; ++j) {                                         \
      float2 v2 = *(const float2*)(rc + j * 2);                           \
      yf[2 * j] = v2.x; yf[2 * j + 1] = v2.y;                             \
    }                                                                     \
  }
#define XSTORE(buf)                                                       \
  {                                                                       \
    _Pragma("unroll")                                                     \
    for (int e = 0; e < 4; ++e) {                                         \
      union { uint4 u; uint32_t w4[4]; } pv;                              \
      _Pragma("unroll")                                                   \
      for (int h = 0; h < 4; ++h)                                         \
        pv.w4[h] = pk2(__float_as_uint(xf4[2 * h][e]),                    \
                       __float_as_uint(xf4[2 * h + 1][e]));               \
      *(uint4*)&sx[buf][(dq * 4 + e) * 40 + ((g ^ sgq) << 3)] = pv.u;     \
    }                                                                     \
  }
#define SOFTMAX(buf)                                                      \
  {                                                                       \
    float yy[10]; float mx = -3.0e38f;                                    \
    _Pragma("unroll")                                                     \
    for (int j = 0; j < 10; ++j) {                                        \
      int cc = cg * 10 + j;                                               \
      yy[j] = yf[j] * sc[cc] + sh[cc];                                    \
      mx = fmaxf(mx, yy[j]);                                              \
    }                                                                     \
    mx = fmaxf(mx, __shfl_xor(mx, 1));                                    \
    mx = fmaxf(mx, __shfl_xor(mx, 2));                                    \
    mx = fmaxf(mx, __shfl_xor(mx, 4));                                    \
    float sum = 0.f;                                                      \
    _Pragma("unroll")                                                     \
    for (int j = 0; j < 10; ++j) { yy[j] = __expf(yy[j] - mx); sum += yy[j]; } \
    sum += __shfl_xor(sum, 1);                                            \
    sum += __shfl_xor(sum, 2);                                            \
    sum += __shfl_xor(sum, 4);                                            \
    float inv = 1.0f / sum;                                               \
    _Pragma("unroll")                                                     \
    for (int j = 0; j < 10; ++j) {                                        \
      int cc = cg * 10 + j;                                               \
      if (cc < 64) sp[buf][cc * 40 + r_] = f2b(yy[j] * inv);              \
    }                                                                     \
  }
#define GEMM(buf)                                                         \
  {                                                                       \
    const uint16_t* sxc = sx[buf];                                        \
    const uint16_t* spc = sp[buf];                                        \
    short8 bfr[4];                                                        \
    _Pragma("unroll")                                                     \
    for (int j = 0; j < 4; ++j)                                           \
      bfr[j] = *(const short8*)&spc[(j * 16 + lr) * 40 + (q << 3)];       \
    __builtin_amdgcn_s_setprio(1);                                        \
    _Pragma("unroll")                                                     \
    for (int m = 0; m < 4; ++m) {                                         \
      int row = w * 64 + m * 16 + lr;                                     \
      int swr = ((row >> 2) + (row >> 4)) & 3;                            \
      short8 af = *(const short8*)&sxc[row * 40 + ((q ^ swr) << 3)];      \
      _Pragma("unroll")                                                   \
      for (int j = 0; j < 4; ++j)                                         \
        acc[m][j] = __builtin_amdgcn_mfma_f32_16x16x32_bf16(af, bfr[j], acc[m][j], 0, 0, 0); \
    }                                                                     \
    __builtin_amdgcn_s_setprio(0);                                        \
    union { uint4 u; uint16_t us[8]; } pv;                                \
    pv.u = *(const uint4*)&spc[kk_ * 40 + (ng << 3)];                     \
    _Pragma("unroll")                                                     \
    for (int i = 0; i < 8; ++i) asum += b2f(pv.us[i]);                    \
  }

  XLOAD(0) RLOAD(0)
  __syncthreads();                 // sc/sh visible
  XSTORE(0) SOFTMAX(0)            // stage chunk0 -> buf0
  XLOAD(1) RLOAD(1)               // prefetch chunk1
  __syncthreads();                 // buf0 published

  for (int c = 0; c < 8; ++c) {
    const int cur = c & 1;
    if (c < 7) {
      XSTORE(cur ^ 1) SOFTMAX(cur ^ 1)   // stage chunk c+1 (disjoint buffer)
      if (c < 6) { XLOAD(c + 2) RLOAD(c + 2) }
    }
    GEMM(cur)
    __syncthreads();               // buf cur free for re-stage; buf cur^1 ready
  }
#undef XLOAD
#undef RLOAD
#undef XSTORE
#undef SOFTMAX
#undef GEMM

  ared[ng * 64 + kk_] = asum;
  __syncthreads();
  if (dh == 0 && t < 64) {
    float a = ared[t] + ared[64 + t] + ared[128 + t] + ared[192 + t];
    apart[((size_t)b * 8 + s) * 64 + t] = a;
  }

  float* vp = vpart + ((size_t)s * 32 + b) * 32768;
#pragma unroll
  for (int m = 0; m < 4; ++m)
#pragma unroll
    for (int j = 0; j < 4; ++j)
#pragma unroll
      for (int r2 = 0; r2 < 4; ++r2)
        vp[(size_t)(dh * 256 + w * 64 + m * 16 + q * 4 + r2) * 64 + j * 16 + lr] =
            acc[m][j][r2];
}

// ---------------------------------------------------------------------------
// K5a: v = sum_s vpart[s] - a_sum*c2 ; write vfull + partial column sumsq.
// float4 over k (16B/lane loads). grid 512 (32 b x 16 dg) x 256.
// ---------------------------------------------------------------------------
__global__ __launch_bounds__(256) void k5a_red(
    const float* __restrict__ vpart, const float* __restrict__ apart,
    const float* __restrict__ c2, float* __restrict__ vfull,
    float* __restrict__ csq) {
  __shared__ float las[64];
  __shared__ float sred[16 * 64];
  const int t = threadIdx.x, b = blockIdx.x >> 4, dg = blockIdx.x & 15;
  if (t < 64) {
    float a = 0.f;
#pragma unroll
    for (int s = 0; s < 8; ++s) a += apart[((size_t)b * 8 + s) * 64 + t];
    las[t] = a;
  }
  __syncthreads();
  const int di = t >> 4, kq = t & 15;
  const float4 lasv = *(const float4*)&las[kq * 4];
  float4 ssq = {0.f, 0.f, 0.f, 0.f};
#pragma unroll
  for (int jj = 0; jj < 2; ++jj) {
    int d = dg * 32 + jj * 16 + di;
    size_t i = (size_t)d * 64 + kq * 4;
    float4 cc = *(const float4*)(c2 + i);
    float4 v;
    v.x = -lasv.x * cc.x; v.y = -lasv.y * cc.y;
    v.z = -lasv.z * cc.z; v.w = -lasv.w * cc.w;
#pragma unroll
    for (int s = 0; s < 8; ++s) {
      float4 p = *(const float4*)(vpart + ((size_t)s * 32 + b) * 32768 + i);
      v.x += p.x; v.y += p.y; v.z += p.z; v.w += p.w;
    }
    *(float4*)(vfull + (size_t)b * 32768 + i) = v;
    ssq.x += v.x * v.x; ssq.y += v.y * v.y;
    ssq.z += v.z * v.z; ssq.w += v.w * v.w;
  }
  *(float4*)&sred[di * 64 + kq * 4] = ssq;
  __syncthreads();
  if (t < 64) {
    float s0 = 0.f;
#pragma unroll
    for (int di2 = 0; di2 < 16; ++di2) s0 += sred[di2 * 64 + t];
    csq[(size_t)blockIdx.x * 64 + t] = s0;
  }
}

// ---------------------------------------------------------------------------
// K5c: linv/gscl recomputed per block from csq (4KB, L2-hot).
// out = vfull * linv[k] * gscl[b]. grid 512 (32b x 16seg) x 256.
// ---------------------------------------------------------------------------
__global__ __launch_bounds__(256) void k5c_norm(
    const float* __restrict__ csq, const float* __restrict__ vfull,
    float* __restrict__ out) {
  __shared__ float lv[64];
  __shared__ float gsv;
  const int t = threadIdx.x, b = blockIdx.x >> 4, seg = blockIdx.x & 15;
  if (t < 64) {                       // wave 0 computes linv + gscl for b
    float ssq = 0.f;
#pragma unroll
    for (int dg = 0; dg < 16; ++dg) ssq += csq[(size_t)(b * 16 + dg) * 64 + t];
    float iv = 1.0f / fmaxf(sqrtf(ssq), 1e-12f);
    lv[t] = iv;
    float contrib = ssq * iv * iv;
#pragma unroll
    for (int o = 1; o < 64; o <<= 1) contrib += __shfl_xor(contrib, o);
    if (t == 0) gsv = 1.0f / fmaxf(sqrtf(contrib), 1e-12f);
  }
  __syncthreads();
  const float gg = gsv;
#pragma unroll
  for (int u = 0; u < 2; ++u) {
    int i = seg * 2048 + u * 1024 + t * 4;
    int k0 = i & 63;
    float4 a = *(const float4*)(vfull + (size_t)b * 32768 + i);
    float4 o;
    o.x = a.x * lv[k0 + 0] * gg;
    o.y = a.y * lv[k0 + 1] * gg;
    o.z = a.z * lv[k0 + 2] * gg;
    o.w = a.w * lv[k0 + 3] * gg;
    *(float4*)&out[(size_t)b * 32768 + i] = o;
  }
}

// ---------------------------------------------------------------------------
// Workspace (bytes), total 60,310,144:
//   cB    @ 0        : 81,920
//   part  @ 81920    : 320*1024*4   =  1,310,720
//   scsh  @ 1392640  : 640
//   raw   @ 1393280  : 65536*80*4   = 20,971,520
//   vpart @ 22364800 : 8*32*32768*4 = 33,554,432
//   vfull @ 55919232 : 32*32768*4   =  4,194,304
//   apart @ 60113536 : 32*8*64*4    =     65,536
//   csq   @ 60179072 : 512*64*4     =    131,072
// ---------------------------------------------------------------------------
extern "C" void kernel_launch(void* const* d_in, const int* in_sizes, int n_in,
                              void* d_out, int out_size, void* d_ws, size_t ws_size,
                              hipStream_t stream) {
  const float* x         = (const float*)d_in[0];
  const float* clusters  = (const float*)d_in[1];
  const float* clusters2 = (const float*)d_in[2];
  const float* gamma     = (const float*)d_in[3];
  const float* beta      = (const float*)d_in[4];
  float* out = (float*)d_out;
  char* ws = (char*)d_ws;

  uint16_t* cB = (uint16_t*)(ws + 0);
  float* part  = (float*)(ws + 81920);
  float* scsh  = (float*)(ws + 1392640);
  float* raw   = (float*)(ws + 1393280);
  float* vpart = (float*)(ws + 22364800);
  float* vfull = (float*)(ws + 55919232);
  float* apart = (float*)(ws + 60113536);
  float* csq   = (float*)(ws + 60179072);

  hipLaunchKernelGGL(k0_prep,   dim3(160),  dim3(256), 0, stream, clusters, cB);
  hipLaunchKernelGGL(k1_gemm1,  dim3(1024), dim3(256), 0, stream, x, cB, raw, part);
  hipLaunchKernelGGL(k2_stats,  dim3(80),   dim3(64),  0, stream, part, gamma, beta, scsh);
  hipLaunchKernelGGL(k34_fused, dim3(512),  dim3(256), 0, stream, x, raw, scsh, vpart, apart);
  hipLaunchKernelGGL(k5a_red,   dim3(512),  dim3(256), 0, stream, vpart, apart, clusters2, vfull, csq);
  hipLaunchKernelGGL(k5c_norm,  dim3(512),  dim3(256), 0, stream, csq, vfull, out);
}

// Round 5
// 245.234 us; speedup vs baseline: 1.0208x; 1.0010x over previous
//
#include <hip/hip_runtime.h>
#include <hip/hip_bf16.h>
#include <stdint.h>

// Problem: B=32, N=2048, D=512, K=64, G=16, M=B*N=65536, C=K+G=80
// Inputs fp32; OUTPUT fp32.
typedef __attribute__((ext_vector_type(8))) short short8;
typedef __attribute__((ext_vector_type(4))) float f32x4;

__device__ __forceinline__ float b2f(uint16_t u) {
  union { uint32_t i; float f; } v; v.i = ((uint32_t)u) << 16; return v.f;
}
__device__ __forceinline__ uint16_t f2b(float f) {   // RNE fp32->bf16
  uint32_t u = __float_as_uint(f);
  return (uint16_t)((u + 0x7FFFu + ((u >> 16) & 1u)) >> 16);
}
// pack two fp32 bit-patterns -> bf16x2 (lo in low half) via v_perm
__device__ __forceinline__ uint32_t pk2(uint32_t lo, uint32_t hi) {
  return __builtin_amdgcn_perm(hi + 0x8000u, lo + 0x8000u, 0x07060302u);
}

// ---------------------------------------------------------------------------
// K0: clusters fp32 [512][80] -> bf16 MFMA B-fragments, [chunk][q][lr] order:
// cB[(((kk*5+n)*4+q)*16+lr)*8+i] = clusters[kk*32+q*8+i][n*16+lr]
// ---------------------------------------------------------------------------
__global__ void k0_prep(const float* __restrict__ clusters,
                        uint16_t* __restrict__ cB) {
  int gid = blockIdx.x * 256 + threadIdx.x;
  if (gid < 40960) {
    int i = gid & 7, chunk = gid >> 3;
    int lr = chunk & 15, q = (chunk >> 4) & 3, c5 = chunk >> 6;
    int n = c5 % 5, kk = c5 / 5;
    cB[gid] = f2b(clusters[(kk * 32 + q * 8 + i) * 80 + n * 16 + lr]);
  }
}

// ---------------------------------------------------------------------------
// K1: raw[65536][80] = bf16(x) @ bf16(clusters)  (MFMA 16x16x32)
//     + per-block column sum/sumsq partials (part TRANSPOSED: part[c][blk]).
// m=1 (64 rows/block, grid 1024), __launch_bounds__(256,4); 2-deep x
// prefetch + 1-deep cB prefetch.
// ---------------------------------------------------------------------------
__global__ __launch_bounds__(256, 4) void k1_gemm1(
    const float* __restrict__ x, const uint16_t* __restrict__ cB,
    float* __restrict__ raw, float* __restrict__ part) {
  __shared__ float sf[1280];
  const int t = threadIdx.x;
  const int w = t >> 6, lane = t & 63, q = lane >> 4, lr = lane & 15;
  const int rbase = blockIdx.x * 64 + w * 16;

  f32x4 acc[5];
#pragma unroll
  for (int n = 0; n < 5; ++n) acc[n] = 0.f;

  const float* xa = x + (size_t)(rbase + lr) * 512 + q * 8;
  const short8* cbq = (const short8*)cB + q * 16 + lr;  // + (kk*5+n)*64

  uint4 u0[2], u1[2];
  u0[0] = *(const uint4*)(xa);          u1[0] = *(const uint4*)(xa + 4);
  u0[1] = *(const uint4*)(xa + 32);     u1[1] = *(const uint4*)(xa + 36);
  short8 bfc[5], bfp[5];
#pragma unroll
  for (int n = 0; n < 5; ++n) bfc[n] = cbq[n * 64];

#pragma unroll
  for (int kk = 0; kk < 16; ++kk) {
    const int si = kk & 1;
    union { short8 s; uint32_t u[4]; } av;
    av.u[0] = pk2(u0[si].x, u0[si].y); av.u[1] = pk2(u0[si].z, u0[si].w);
    av.u[2] = pk2(u1[si].x, u1[si].y); av.u[3] = pk2(u1[si].z, u1[si].w);
    if (kk < 15) {
#pragma unroll
      for (int n = 0; n < 5; ++n) bfp[n] = cbq[((kk + 1) * 5 + n) * 64];
    }
    if (kk < 14) {
      u0[si] = *(const uint4*)(xa + (kk + 2) * 32);
      u1[si] = *(const uint4*)(xa + (kk + 2) * 32 + 4);
    }
#pragma unroll
    for (int n = 0; n < 5; ++n)
      acc[n] = __builtin_amdgcn_mfma_f32_16x16x32_bf16(av.s, bfc[n], acc[n], 0, 0, 0);
#pragma unroll
    for (int n = 0; n < 5; ++n) bfc[n] = bfp[n];
  }

  float sums[5], sqs[5];
#pragma unroll
  for (int n = 0; n < 5; ++n) {
    float s = 0.f, qq = 0.f;
#pragma unroll
    for (int r = 0; r < 4; ++r) {
      float v = acc[n][r];
      s += v; qq += v * v;
      raw[(size_t)(rbase + q * 4 + r) * 80 + n * 16 + lr] = v;
    }
    s += __shfl_xor(s, 16);  s += __shfl_xor(s, 32);
    qq += __shfl_xor(qq, 16); qq += __shfl_xor(qq, 32);
    sums[n] = s; sqs[n] = qq;
  }

  if (lane < 16) {
#pragma unroll
    for (int n = 0; n < 5; ++n) {
      sf[w * 160 + n * 16 + lr] = sums[n];
      sf[640 + w * 160 + n * 16 + lr] = sqs[n];
    }
  }
  __syncthreads();
  if (t < 160) {
    float a0 = sf[t] + sf[160 + t] + sf[320 + t] + sf[480 + t];
    float b0 = sf[640 + t] + sf[800 + t] + sf[960 + t] + sf[1120 + t];
    part[(size_t)t * 1024 + blockIdx.x] = a0;            // transposed layout
    part[(size_t)(160 + t) * 1024 + blockIdx.x] = b0;
  }
}

// ---------------------------------------------------------------------------
// K2: BN stats -> scale[80] | shift[80]. grid 80 x 64. Coalesced reads.
// ---------------------------------------------------------------------------
__global__ __launch_bounds__(64) void k2_stats(
    const float* __restrict__ part, const float* __restrict__ gamma,
    const float* __restrict__ beta, float* __restrict__ scsh) {
  int c = blockIdx.x, t = threadIdx.x;
  const float* p1 = part + (size_t)c * 1024;
  const float* p2 = part + (size_t)(160 + c) * 1024;
  float s1 = 0.f, s2 = 0.f;
#pragma unroll
  for (int p = 0; p < 1024; p += 64) { s1 += p1[p + t]; s2 += p2[p + t]; }
#pragma unroll
  for (int o = 1; o < 64; o <<= 1) { s1 += __shfl_xor(s1, o); s2 += __shfl_xor(s2, o); }
  if (t == 0) {
    float mean = s1 * (1.f / 65536.f);
    float var = s2 * (1.f / 65536.f) - mean * mean;
    float sc = rsqrtf(var + 1e-5f) * gamma[c];
    scsh[c] = sc;
    scsh[80 + c] = beta[c] - mean * sc;
  }
}

// ---------------------------------------------------------------------------
// k34: fused BN + softmax + GEMM2. R5: s-split 8 -> 4 (each block does 512 n
// = 16 chunks) halving the vpart round-trip (33.5 -> 16.8 MB each way).
// Grid 256 = dh(2) x s(4) x b(32); 256 thr; 8 waves/CU (occupancy-insensitive
// per R2/R3 probes; 2-deep prefetch x 256 blocks keeps BW-latency product).
// vpart[s][b][d][k] partials; apart[b][s][k] = per-slice sum of p.
// ---------------------------------------------------------------------------
__global__ __launch_bounds__(256, 2) void k34_fused(
    const float* __restrict__ x, const float* __restrict__ raw_,
    const float* __restrict__ scsh, float* __restrict__ vpart,
    float* __restrict__ apart) {
  __shared__ __align__(16) uint16_t sx[2][256 * 40];  // 40,960 B  [d][n] bf16
  __shared__ __align__(16) uint16_t sp[2][64 * 40];   // 10,240 B  [k][n] bf16
  __shared__ float sc[80], sh[80];
  __shared__ float ared[4 * 64];

  const int t = threadIdx.x;
  const int b = blockIdx.x & 31;
  const int s = (blockIdx.x >> 5) & 3;
  const int dh = blockIdx.x >> 7;
  const int w = t >> 6, lane = t & 63, q = lane >> 4, lr = lane & 15;

  const int dq = t & 63, g = t >> 6;                  // x staging: d-quad, n-octet
  const int sgq = (dq + (dq >> 2)) & 3;               // swizzle slot (same for e=0..3)
  const int r_ = t >> 3, cg = t & 7;                  // softmax: row, 10-col grp
  const int kk_ = t & 63, ng = t >> 6;                // a_sum: k, n-octet group

  if (t < 80) sc[t] = scsh[t];
  else if (t < 160) sh[t - 80] = scsh[t];

  const float* xb = x + ((size_t)b * 2048 + (size_t)s * 512) * 512 + dh * 256;
  const float* rawb = raw_ + ((size_t)b * 2048 + (size_t)s * 512) * 80;

  f32x4 acc[4][4];
#pragma unroll
  for (int m = 0; m < 4; ++m)
#pragma unroll
    for (int j = 0; j < 4; ++j) acc[m][j] = 0.f;

  f32x4 xf4[8];
  float yf[10];
  float asum = 0.f;

#define XLOAD(c)                                                          \
  {                                                                       \
    const float* xc = xb + (size_t)((c) * 32 + g * 8) * 512 + dq * 4;     \
    _Pragma("unroll")                                                     \
    for (int jj = 0; jj < 8; ++jj)                                        \
      xf4[jj] = *(const f32x4*)(xc + (size_t)jj * 512);                   \
  }
#define RLOAD(c)                                                          \
  {                                                                       \
    const float* rc = rawb + (size_t)((c) * 32 + r_) * 80 + cg * 10;      \
    _Pragma("unroll")                                                     \
    for (int j = 0; j < 5; ++j) {                                         \
      float2 v2 = *(const float2*)(rc + j * 2);                           \
      yf[2 * j] = v2.x; yf[2 * j + 1] = v2.y;                             \
    }                                                                     \
  }
#define XSTORE(buf)                                                       \
  {                                                                       \
    _Pragma("unroll")                                                     \
    for (int e = 0; e < 4; ++e) {                                         \
      union { uint4 u; uint32_t w4[4]; } pv;                              \
      _Pragma("unroll")                                                   \
      for (int h = 0; h < 4; ++h)                                         \
        pv.w4[h] = pk2(__float_as_uint(xf4[2 * h][e]),                    \
                       __float_as_uint(xf4[2 * h + 1][e]));               \
      *(uint4*)&sx[buf][(dq * 4 + e) * 40 + ((g ^ sgq) << 3)] = pv.u;     \
    }                                                                     \
  }
#define SOFTMAX(buf)                                                      \
  {                                                                       \
    float yy[10]; float mx = -3.0e38f;                                    \
    _Pragma("unroll")                                                     \
    for (int j = 0; j < 10; ++j) {                                        \
      int cc = cg * 10 + j;                                               \
      yy[j] = yf[j] * sc[cc] + sh[cc];                                    \
      mx = fmaxf(mx, yy[j]);                                              \
    }                                                                     \
    mx = fmaxf(mx, __shfl_xor(mx, 1));                                    \
    mx = fmaxf(mx, __shfl_xor(mx, 2));                                    \
    mx = fmaxf(mx, __shfl_xor(mx, 4));                                    \
    float sum = 0.f;                                                      \
    _Pragma("unroll")                                                     \
    for (int j = 0; j < 10; ++j) { yy[j] = __expf(yy[j] - mx); sum += yy[j]; } \
    sum += __shfl_xor(sum, 1);                                            \
    sum += __shfl_xor(sum, 2);                                            \
    sum += __shfl_xor(sum, 4);                                            \
    float inv = 1.0f / sum;                                               \
    _Pragma("unroll")                                                     \
    for (int j = 0; j < 10; ++j) {                                        \
      int cc = cg * 10 + j;                                               \
      if (cc < 64) sp[buf][cc * 40 + r_] = f2b(yy[j] * inv);              \
    }                                                                     \
  }
#define GEMM(buf)                                                         \
  {                                                                       \
    const uint16_t* sxc = sx[buf];                                        \
    const uint16_t* spc = sp[buf];                                        \
    short8 bfr[4];                                                        \
    _Pragma("unroll")                                                     \
    for (int j = 0; j < 4; ++j)                                           \
      bfr[j] = *(const short8*)&spc[(j * 16 + lr) * 40 + (q << 3)];       \
    __builtin_amdgcn_s_setprio(1);                                        \
    _Pragma("unroll")                                                     \
    for (int m = 0; m < 4; ++m) {                                         \
      int row = w * 64 + m * 16 + lr;                                     \
      int swr = ((row >> 2) + (row >> 4)) & 3;                            \
      short8 af = *(const short8*)&sxc[row * 40 + ((q ^ swr) << 3)];      \
      _Pragma("unroll")                                                   \
      for (int j = 0; j < 4; ++j)                                         \
        acc[m][j] = __builtin_amdgcn_mfma_f32_16x16x32_bf16(af, bfr[j], acc[m][j], 0, 0, 0); \
    }                                                                     \
    __builtin_amdgcn_s_setprio(0);                                        \
    union { uint4 u; uint16_t us[8]; } pv;                                \
    pv.u = *(const uint4*)&spc[kk_ * 40 + (ng << 3)];                     \
    _Pragma("unroll")                                                     \
    for (int i = 0; i < 8; ++i) asum += b2f(pv.us[i]);                    \
  }

  XLOAD(0) RLOAD(0)
  __syncthreads();                 // sc/sh visible
  XSTORE(0) SOFTMAX(0)            // stage chunk0 -> buf0
  XLOAD(1) RLOAD(1)               // prefetch chunk1
  __syncthreads();                 // buf0 published

  for (int c = 0; c < 16; ++c) {
    const int cur = c & 1;
    if (c < 15) {
      XSTORE(cur ^ 1) SOFTMAX(cur ^ 1)   // stage chunk c+1 (disjoint buffer)
      if (c < 14) { XLOAD(c + 2) RLOAD(c + 2) }
    }
    GEMM(cur)
    __syncthreads();               // buf cur free for re-stage; buf cur^1 ready
  }
#undef XLOAD
#undef RLOAD
#undef XSTORE
#undef SOFTMAX
#undef GEMM

  ared[ng * 64 + kk_] = asum;
  __syncthreads();
  if (dh == 0 && t < 64) {
    float a = ared[t] + ared[64 + t] + ared[128 + t] + ared[192 + t];
    apart[((size_t)b * 4 + s) * 64 + t] = a;
  }

  float* vp = vpart + ((size_t)s * 32 + b) * 32768;
#pragma unroll
  for (int m = 0; m < 4; ++m)
#pragma unroll
    for (int j = 0; j < 4; ++j)
#pragma unroll
      for (int r2 = 0; r2 < 4; ++r2)
        vp[(size_t)(dh * 256 + w * 64 + m * 16 + q * 4 + r2) * 64 + j * 16 + lr] =
            acc[m][j][r2];
}

// ---------------------------------------------------------------------------
// K5a: v = sum_s vpart[s] - a_sum*c2 ; write vfull + partial column sumsq.
// float4 over k (16B/lane loads). 4 s-slices. grid 512 (32 b x 16 dg) x 256.
// ---------------------------------------------------------------------------
__global__ __launch_bounds__(256) void k5a_red(
    const float* __restrict__ vpart, const float* __restrict__ apart,
    const float* __restrict__ c2, float* __restrict__ vfull,
    float* __restrict__ csq) {
  __shared__ float las[64];
  __shared__ float sred[16 * 64];
  const int t = threadIdx.x, b = blockIdx.x >> 4, dg = blockIdx.x & 15;
  if (t < 64) {
    float a = 0.f;
#pragma unroll
    for (int s = 0; s < 4; ++s) a += apart[((size_t)b * 4 + s) * 64 + t];
    las[t] = a;
  }
  __syncthreads();
  const int di = t >> 4, kq = t & 15;
  const float4 lasv = *(const float4*)&las[kq * 4];
  float4 ssq = {0.f, 0.f, 0.f, 0.f};
#pragma unroll
  for (int jj = 0; jj < 2; ++jj) {
    int d = dg * 32 + jj * 16 + di;
    size_t i = (size_t)d * 64 + kq * 4;
    float4 cc = *(const float4*)(c2 + i);
    float4 v;
    v.x = -lasv.x * cc.x; v.y = -lasv.y * cc.y;
    v.z = -lasv.z * cc.z; v.w = -lasv.w * cc.w;
#pragma unroll
    for (int s = 0; s < 4; ++s) {
      float4 p = *(const float4*)(vpart + ((size_t)s * 32 + b) * 32768 + i);
      v.x += p.x; v.y += p.y; v.z += p.z; v.w += p.w;
    }
    *(float4*)(vfull + (size_t)b * 32768 + i) = v;
    ssq.x += v.x * v.x; ssq.y += v.y * v.y;
    ssq.z += v.z * v.z; ssq.w += v.w * v.w;
  }
  *(float4*)&sred[di * 64 + kq * 4] = ssq;
  __syncthreads();
  if (t < 64) {
    float s0 = 0.f;
#pragma unroll
    for (int di2 = 0; di2 < 16; ++di2) s0 += sred[di2 * 64 + t];
    csq[(size_t)blockIdx.x * 64 + t] = s0;
  }
}

// ---------------------------------------------------------------------------
// K5c: linv/gscl recomputed per block from csq (4KB, L2-hot).
// out = vfull * linv[k] * gscl[b]. grid 512 (32b x 16seg) x 256.
// ---------------------------------------------------------------------------
__global__ __launch_bounds__(256) void k5c_norm(
    const float* __restrict__ csq, const float* __restrict__ vfull,
    float* __restrict__ out) {
  __shared__ float lv[64];
  __shared__ float gsv;
  const int t = threadIdx.x, b = blockIdx.x >> 4, seg = blockIdx.x & 15;
  if (t < 64) {                       // wave 0 computes linv + gscl for b
    float ssq = 0.f;
#pragma unroll
    for (int dg = 0; dg < 16; ++dg) ssq += csq[(size_t)(b * 16 + dg) * 64 + t];
    float iv = 1.0f / fmaxf(sqrtf(ssq), 1e-12f);
    lv[t] = iv;
    float contrib = ssq * iv * iv;
#pragma unroll
    for (int o = 1; o < 64; o <<= 1) contrib += __shfl_xor(contrib, o);
    if (t == 0) gsv = 1.0f / fmaxf(sqrtf(contrib), 1e-12f);
  }
  __syncthreads();
  const float gg = gsv;
#pragma unroll
  for (int u = 0; u < 2; ++u) {
    int i = seg * 2048 + u * 1024 + t * 4;
    int k0 = i & 63;
    float4 a = *(const float4*)(vfull + (size_t)b * 32768 + i);
    float4 o;
    o.x = a.x * lv[k0 + 0] * gg;
    o.y = a.y * lv[k0 + 1] * gg;
    o.z = a.z * lv[k0 + 2] * gg;
    o.w = a.w * lv[k0 + 3] * gg;
    *(float4*)&out[(size_t)b * 32768 + i] = o;
  }
}

// ---------------------------------------------------------------------------
// Workspace (bytes), total 43,500,160:
//   cB    @ 0        : 81,920
//   part  @ 81920    : 320*1024*4   =  1,310,720
//   scsh  @ 1392640  : 640
//   raw   @ 1393280  : 65536*80*4   = 20,971,520
//   vpart @ 22364800 : 4*32*32768*4 = 16,777,216
//   vfull @ 39142016 : 32*32768*4   =  4,194,304
//   apart @ 43336320 : 32*4*64*4    =     32,768
//   csq   @ 43369088 : 512*64*4     =    131,072
// ---------------------------------------------------------------------------
extern "C" void kernel_launch(void* const* d_in, const int* in_sizes, int n_in,
                              void* d_out, int out_size, void* d_ws, size_t ws_size,
                              hipStream_t stream) {
  const float* x         = (const float*)d_in[0];
  const float* clusters  = (const float*)d_in[1];
  const float* clusters2 = (const float*)d_in[2];
  const float* gamma     = (const float*)d_in[3];
  const float* beta      = (const float*)d_in[4];
  float* out = (float*)d_out;
  char* ws = (char*)d_ws;

  uint16_t* cB = (uint16_t*)(ws + 0);
  float* part  = (float*)(ws + 81920);
  float* scsh  = (float*)(ws + 1392640);
  float* raw   = (float*)(ws + 1393280);
  float* vpart = (float*)(ws + 22364800);
  float* vfull = (float*)(ws + 39142016);
  float* apart = (float*)(ws + 43336320);
  float* csq   = (float*)(ws + 43369088);

  hipLaunchKernelGGL(k0_prep,   dim3(160),  dim3(256), 0, stream, clusters, cB);
  hipLaunchKernelGGL(k1_gemm1,  dim3(1024), dim3(256), 0, stream, x, cB, raw, part);
  hipLaunchKernelGGL(k2_stats,  dim3(80),   dim3(64),  0, stream, part, gamma, beta, scsh);
  hipLaunchKernelGGL(k34_fused, dim3(256),  dim3(256), 0, stream, x, raw, scsh, vpart, apart);
  hipLaunchKernelGGL(k5a_red,   dim3(512),  dim3(256), 0, stream, vpart, apart, clusters2, vfull, csq);
  hipLaunchKernelGGL(k5c_norm,  dim3(512),  dim3(256), 0, stream, csq, vfull, out);
}